// Round 9
// baseline (294.441 us; speedup 1.0000x reference)
//
#include <hip/hip_runtime.h>
#include <hip/hip_fp16.h>
#include <math.h>

#define NNODES 50000
#define NEDGES 800000
#define NCHUNK 13              // src chunk = src >> 12 (4096 nodes/chunk)
#define NB2 (NNODES * NCHUNK)  // 650000 (dst,chunk) buckets

typedef _Float16 half8 __attribute__((ext_vector_type(8)));
typedef float floatx4 __attribute__((ext_vector_type(4)));

// ---------------- chunk-ordered CSR construction ----------------

__global__ void zero_i32(int* __restrict__ p, int n) {
    int i = blockIdx.x * 256 + threadIdx.x;
    if (i < n) p[i] = 0;
}

// histogram over (dst, src-chunk) buckets
__global__ void hist2_kernel(const int* __restrict__ src, const int* __restrict__ dst,
                             int* __restrict__ cnt2, int e) {
    int i = blockIdx.x * 256 + threadIdx.x;
    if (i < e) atomicAdd(&cnt2[dst[i] * NCHUNK + (src[i] >> 12)], 1);
}

// block-local inclusive scan: out[i+1] = sum(counts[block_start..i]), bsums[b]=block total
__global__ void scan1_kernel(const int* __restrict__ counts, int* __restrict__ out,
                             int* __restrict__ bsums, int n) {
    __shared__ int s[256];
    int tid = threadIdx.x;
    int i = blockIdx.x * 256 + tid;
    int v = (i < n) ? counts[i] : 0;
    s[tid] = v;
    __syncthreads();
    #pragma unroll
    for (int o = 1; o < 256; o <<= 1) {
        int t = (tid >= o) ? s[tid - o] : 0;
        __syncthreads();
        s[tid] += t;
        __syncthreads();
    }
    if (i < n) out[i + 1] = s[tid];
    if (tid == 255) bsums[blockIdx.x] = s[255];
}

// exclusive scan in place (nb <= 256)
__global__ void scan2_kernel(int* __restrict__ bsums, int nb) {
    __shared__ int s[256];
    int tid = threadIdx.x;
    int v = (tid < nb) ? bsums[tid] : 0;
    s[tid] = v;
    __syncthreads();
    #pragma unroll
    for (int o = 1; o < 256; o <<= 1) {
        int t = (tid >= o) ? s[tid - o] : 0;
        __syncthreads();
        s[tid] += t;
        __syncthreads();
    }
    if (tid < nb) bsums[tid] = s[tid] - v;  // exclusive
}

// add per-block exclusive offsets; set out[0]=0; zero cursor scratch
__global__ void scan3_kernel(int* __restrict__ out, const int* __restrict__ bsums,
                             int* __restrict__ cursor, int n) {
    int i = blockIdx.x * 256 + threadIdx.x;
    if (i < n) {
        out[i + 1] += bsums[blockIdx.x];
        cursor[i] = 0;
    }
    if (i == 0) out[0] = 0;
}

// row_ptr[i] = cp[i*NCHUNK]; row_ptr[NNODES] = NEDGES
__global__ void rowptr_kernel(const int* __restrict__ cp, int* __restrict__ row_ptr) {
    int i = blockIdx.x * 256 + threadIdx.x;
    if (i < NNODES) row_ptr[i] = cp[i * NCHUNK];
    if (i == NNODES) row_ptr[NNODES] = NEDGES;
}

__global__ void fill2_kernel(const int* __restrict__ src, const int* __restrict__ dst,
                             const int* __restrict__ cp, int* __restrict__ cursor,
                             int* __restrict__ csr_src, int e) {
    int i = blockIdx.x * 256 + threadIdx.x;
    if (i < e) {
        int s_ = src[i];
        int b = dst[i] * NCHUNK + (s_ >> 12);
        int pos = atomicAdd(&cursor[b], 1);
        csr_src[cp[b] + pos] = s_;
    }
}

// ---------------- MFMA GEMM + fused attention logits ----------------
// H[n][M] (fp16) = A[n][128] @ W[128][M], fp32 accumulate via
// v_mfma_f32_16x16x32_f16. Tile 128x64, whole K=128 in LDS, 4 waves.

template <int CH, bool AF32, int LAYER>
__global__ __launch_bounds__(256, 3) void gemm_mfma(const void* __restrict__ A_,
                                                    const float* __restrict__ Wf,
                                                    const float* __restrict__ a_src,
                                                    const float* __restrict__ a_dst,
                                                    __half* __restrict__ H,
                                                    float* __restrict__ asrc,
                                                    float* __restrict__ adst, int n, int M) {
    __shared__ __half As[128][136];
    __shared__ __half Ws[64][136];
    float* scrf = (float*)&As[0][0];  // CH64 overlay: [2][128][2] floats
    int tid = threadIdx.x;
    int row0 = blockIdx.x * 128;
    int col0 = blockIdx.y * 64;

    if constexpr (AF32) {
        const float* Af = (const float*)A_;
        #pragma unroll
        for (int it = 0; it < 8; ++it) {
            int flat = tid + it * 256;
            int r = flat >> 4;
            int kq = (flat & 15) * 8;
            int gr = row0 + r;
            float4 v0 = {0.f, 0.f, 0.f, 0.f}, v1 = {0.f, 0.f, 0.f, 0.f};
            if (gr < n) {
                v0 = *(const float4*)&Af[(size_t)gr * 128 + kq];
                v1 = *(const float4*)&Af[(size_t)gr * 128 + kq + 4];
            }
            __half2 h0 = __floats2half2_rn(v0.x, v0.y);
            __half2 h1 = __floats2half2_rn(v0.z, v0.w);
            __half2 h2 = __floats2half2_rn(v1.x, v1.y);
            __half2 h3 = __floats2half2_rn(v1.z, v1.w);
            uint4 st = {*(unsigned*)&h0, *(unsigned*)&h1, *(unsigned*)&h2, *(unsigned*)&h3};
            *(uint4*)&As[r][kq] = st;
        }
    } else {
        const __half* Ah = (const __half*)A_;
        #pragma unroll
        for (int it = 0; it < 8; ++it) {
            int flat = tid + it * 256;
            int r = flat >> 4;
            int kq = (flat & 15) * 8;
            int gr = row0 + r;
            float4 v = {0.f, 0.f, 0.f, 0.f};
            if (gr < n) v = *(const float4*)&Ah[(size_t)gr * 128 + kq];
            *(float4*)&As[r][kq] = v;
        }
    }
    #pragma unroll
    for (int it = 0; it < 4; ++it) {
        int flat = tid + it * 256;
        int kp = flat >> 4;
        int c4 = (flat & 15) * 4;
        int k = kp * 2;
        float4 va = *(const float4*)&Wf[(size_t)k * M + col0 + c4];
        float4 vb = *(const float4*)&Wf[(size_t)(k + 1) * M + col0 + c4];
        *(__half2*)&Ws[c4 + 0][k] = __floats2half2_rn(va.x, vb.x);
        *(__half2*)&Ws[c4 + 1][k] = __floats2half2_rn(va.y, vb.y);
        *(__half2*)&Ws[c4 + 2][k] = __floats2half2_rn(va.z, vb.z);
        *(__half2*)&Ws[c4 + 3][k] = __floats2half2_rn(va.w, vb.w);
    }
    __syncthreads();

    int lane = tid & 63;
    int wid = tid >> 6;
    int wm = (wid >> 1) * 64;
    int wn = (wid & 1) * 32;
    int l15 = lane & 15;
    int l4 = lane >> 4;

    floatx4 acc[4][2];
    #pragma unroll
    for (int mf = 0; mf < 4; ++mf)
        #pragma unroll
        for (int nf = 0; nf < 2; ++nf) {
            floatx4 z = {0.f, 0.f, 0.f, 0.f};
            acc[mf][nf] = z;
        }

    #pragma unroll
    for (int ks = 0; ks < 4; ++ks) {
        int kb = ks * 32 + l4 * 8;
        half8 b0 = *(const half8*)&Ws[wn + l15][kb];
        half8 b1 = *(const half8*)&Ws[wn + 16 + l15][kb];
        #pragma unroll
        for (int mf = 0; mf < 4; ++mf) {
            half8 a = *(const half8*)&As[wm + mf * 16 + l15][kb];
            acc[mf][0] = __builtin_amdgcn_mfma_f32_16x16x32_f16(a, b0, acc[mf][0], 0, 0, 0);
            acc[mf][1] = __builtin_amdgcn_mfma_f32_16x16x32_f16(a, b1, acc[mf][1], 0, 0, 0);
        }
    }
    if constexpr (CH == 64) __syncthreads();

    #pragma unroll
    for (int mf = 0; mf < 4; ++mf)
        #pragma unroll
        for (int r = 0; r < 4; ++r) {
            int gr = row0 + wm + mf * 16 + l4 * 4 + r;
            if (gr < n) {
                H[(size_t)gr * M + col0 + wn + l15] = __float2half(acc[mf][0][r]);
                H[(size_t)gr * M + col0 + wn + 16 + l15] = __float2half(acc[mf][1][r]);
            }
        }

    int hw = (col0 + wn) / CH;
    int cb = (col0 + wn) % CH;
    float vs0 = a_src[hw * CH + cb + l15];
    float vs1 = a_src[hw * CH + cb + 16 + l15];
    float vd0 = a_dst[hw * CH + cb + l15];
    float vd1 = a_dst[hw * CH + cb + 16 + l15];

    #pragma unroll
    for (int mf = 0; mf < 4; ++mf)
        #pragma unroll
        for (int r = 0; r < 4; ++r) {
            float ss = acc[mf][0][r] * vs0 + acc[mf][1][r] * vs1;
            float sd = acc[mf][0][r] * vd0 + acc[mf][1][r] * vd1;
            #pragma unroll
            for (int o = 1; o < 16; o <<= 1) {
                ss += __shfl_xor(ss, o);
                sd += __shfl_xor(sd, o);
            }
            if (l15 == 0) {
                int ri = wm + mf * 16 + l4 * 4 + r;
                if constexpr (CH == 32) {
                    int gr = row0 + ri;
                    if (gr < n) {
                        asrc[(size_t)gr * 4 + hw] = ss;
                        adst[(size_t)gr * 4 + hw] = sd;
                    }
                } else {
                    scrf[((wid & 1) * 128 + ri) * 2 + 0] = ss;
                    scrf[((wid & 1) * 128 + ri) * 2 + 1] = sd;
                }
            }
        }
    if constexpr (CH == 64) {
        __syncthreads();
        if (tid < 128) {
            int gr = row0 + tid;
            if (gr < n) {
                int head = col0 / 64;
                asrc[(size_t)gr * 4 + head] = scrf[tid * 2 + 0] + scrf[(128 + tid) * 2 + 0];
                adst[(size_t)gr * 4 + head] = scrf[tid * 2 + 1] + scrf[(128 + tid) * 2 + 1];
            }
        }
    }
}

// ---------------- segment softmax + weighted aggregation ----------------
// Unchanged from R8 (the csr ordering change is external): one wave per dst
// node, LDS-staged p/src, supersteps of 8 in-flight 8B gathers.

template <int CPL, bool MEAN, int LAYER>
__global__ __launch_bounds__(256) void aggregate_kernel(
    const __half* __restrict__ h, const float* __restrict__ asrc,
    const float* __restrict__ adst, const int* __restrict__ csr_src,
    const int* __restrict__ row_ptr, const float* __restrict__ bias,
    void* __restrict__ out_, int n) {
    __shared__ float lds[4][332];
    int wid = threadIdx.x >> 6;
    int lane = threadIdx.x & 63;
    int node = blockIdx.x * 4 + wid;
    if (node >= n) return;
    float* Wp = lds[wid];
    int* Ws = (int*)&lds[wid][264];
    int start = row_ptr[node];
    int end = row_ptr[node + 1];
    float4 ad = *(const float4*)&adst[(size_t)node * 4];

    int l32, head, j_off;
    if constexpr (CPL == 2) {
        l32 = lane & 31; head = l32 >> 3; j_off = lane >> 5;
    } else {
        l32 = lane; head = lane >> 4; j_off = 0;
    }
    int hoff = head * 66;

    float acc0 = 0.f, acc1 = 0.f, acc2 = 0.f, acc3 = 0.f, pw = 0.f;

    for (int base = start; base < end; base += 64) {
        int cnt = end - base;
        if (cnt > 64) cnt = 64;
        int s = 0;
        float4 pv = {0.f, 0.f, 0.f, 0.f};
        if (lane < cnt) {
            s = csr_src[base + lane];
            float4 a = *(const float4*)&asrc[(size_t)s * 4];
            float e0 = a.x + ad.x; e0 = (e0 > 0.f) ? e0 : 0.2f * e0;
            float e1 = a.y + ad.y; e1 = (e1 > 0.f) ? e1 : 0.2f * e1;
            float e2 = a.z + ad.z; e2 = (e2 > 0.f) ? e2 : 0.2f * e2;
            float e3 = a.w + ad.w; e3 = (e3 > 0.f) ? e3 : 0.2f * e3;
            pv.x = __expf(e0); pv.y = __expf(e1); pv.z = __expf(e2); pv.w = __expf(e3);
        }
        Wp[0 * 66 + lane] = pv.x;
        Wp[1 * 66 + lane] = pv.y;
        Wp[2 * 66 + lane] = pv.z;
        Wp[3 * 66 + lane] = pv.w;
        Ws[lane] = s;
        __builtin_amdgcn_wave_barrier();
        asm volatile("" ::: "memory");
        if constexpr (CPL == 2) {
            for (int jj = 0; jj < cnt; jj += 16) {
                float w[8]; int sa[8];
                #pragma unroll
                for (int u = 0; u < 8; ++u) {
                    int j = jj + 2 * u + j_off;
                    w[u] = Wp[hoff + j];
                    sa[u] = Ws[j];
                }
                float2 v[8];
                #pragma unroll
                for (int u = 0; u < 8; ++u)
                    v[u] = *(const float2*)(h + (size_t)sa[u] * 128 + l32 * 4);
                #pragma unroll
                for (int u = 0; u < 8; ++u) {
                    float2 f01 = __half22float2(((const __half2*)&v[u])[0]);
                    float2 f23 = __half22float2(((const __half2*)&v[u])[1]);
                    acc0 += w[u] * f01.x;
                    acc1 += w[u] * f01.y;
                    acc2 += w[u] * f23.x;
                    acc3 += w[u] * f23.y;
                    pw += w[u];
                }
            }
        } else {
            for (int jj = 0; jj < cnt; jj += 8) {
                float w[8]; int sa[8];
                #pragma unroll
                for (int u = 0; u < 8; ++u) {
                    int j = jj + u;
                    w[u] = Wp[hoff + j];
                    sa[u] = Ws[j];
                }
                float2 v[8];
                #pragma unroll
                for (int u = 0; u < 8; ++u)
                    v[u] = *(const float2*)(h + (size_t)sa[u] * 256 + lane * 4);
                #pragma unroll
                for (int u = 0; u < 8; ++u) {
                    float2 f01 = __half22float2(((const __half2*)&v[u])[0]);
                    float2 f23 = __half22float2(((const __half2*)&v[u])[1]);
                    acc0 += w[u] * f01.x;
                    acc1 += w[u] * f01.y;
                    acc2 += w[u] * f23.x;
                    acc3 += w[u] * f23.y;
                    pw += w[u];
                }
            }
        }
        __builtin_amdgcn_wave_barrier();
        asm volatile("" ::: "memory");
    }

    if constexpr (!MEAN) {
        acc0 += __shfl_xor(acc0, 32);
        acc1 += __shfl_xor(acc1, 32);
        acc2 += __shfl_xor(acc2, 32);
        acc3 += __shfl_xor(acc3, 32);
        pw += __shfl_xor(pw, 32);
        if (lane < 32) {
            float inv = 1.f / (pw + 1e-16f);
            float4 b = *(const float4*)&bias[l32 * 4];
            __half* out = (__half*)out_;
            __half2 ha = __floats2half2_rn(acc0 * inv + b.x, acc1 * inv + b.y);
            __half2 hb = __floats2half2_rn(acc2 * inv + b.z, acc3 * inv + b.w);
            uint2 st = {*(unsigned int*)&ha, *(unsigned int*)&hb};
            *(uint2*)&out[(size_t)node * 128 + l32 * 4] = st;
        }
    } else {
        float inv = 1.f / (pw + 1e-16f);
        float r0 = acc0 * inv, r1 = acc1 * inv, r2 = acc2 * inv, r3 = acc3 * inv;
        r0 += __shfl_xor(r0, 16); r0 += __shfl_xor(r0, 32);
        r1 += __shfl_xor(r1, 16); r1 += __shfl_xor(r1, 32);
        r2 += __shfl_xor(r2, 16); r2 += __shfl_xor(r2, 32);
        r3 += __shfl_xor(r3, 16); r3 += __shfl_xor(r3, 32);
        if (lane < 16) {
            float* out = (float*)out_;
            float4 b = *(const float4*)&bias[lane * 4];
            float4 o;
            o.x = 0.25f * r0 + b.x;
            o.y = 0.25f * r1 + b.y;
            o.z = 0.25f * r2 + b.z;
            o.w = 0.25f * r3 + b.w;
            *(float4*)&out[(size_t)node * 64 + lane * 4] = o;
        }
    }
}

// ---------------- launch ----------------

extern "C" void kernel_launch(void* const* d_in, const int* in_sizes, int n_in,
                              void* d_out, int out_size, void* d_ws, size_t ws_size,
                              hipStream_t stream) {
    const float* x = (const float*)d_in[0];
    const int* ei = (const int*)d_in[1];
    const int* src = ei;
    const int* dst = ei + NEDGES;
    const float* W1 = (const float*)d_in[2];
    const float* as1 = (const float*)d_in[3];
    const float* ad1 = (const float*)d_in[4];
    const float* b1 = (const float*)d_in[5];
    const float* W2 = (const float*)d_in[6];
    const float* as2 = (const float*)d_in[7];
    const float* ad2 = (const float*)d_in[8];
    const float* b2 = (const float*)d_in[9];
    const float* W3 = (const float*)d_in[10];
    const float* as3 = (const float*)d_in[11];
    const float* ad3 = (const float*)d_in[12];
    const float* b3 = (const float*)d_in[13];

    char* ws = (char*)d_ws;
    size_t off = 0;
    auto take = [&](size_t bytes) -> char* {
        char* p = ws + off;
        off = (off + bytes + 255) & ~(size_t)255;
        return p;
    };
    int* csr = (int*)take((size_t)NEDGES * 4);
    int* row_ptr = (int*)take((size_t)(NNODES + 1) * 4);
    int* cnt2 = (int*)take((size_t)NB2 * 4);
    int* cp = (int*)take((size_t)(NB2 + 1) * 4);
    int* cursor2 = (int*)take((size_t)NB2 * 4);
    int* bs1 = (int*)take(2608 * 4);
    int* bs1s = (int*)take(2609 * 4);
    int* bs2 = (int*)take(64 * 4);
    float* asrc = (float*)take((size_t)NNODES * 4 * 4);
    float* adst = (float*)take((size_t)NNODES * 4 * 4);
    __half* hbuf = (__half*)take((size_t)NNODES * 256 * 2);
    __half* buf1h = (__half*)take((size_t)NNODES * 128 * 2);
    float* outp = (float*)d_out;

    int nbB = (NB2 + 255) / 256;        // 2540
    int nbE = (NEDGES + 255) / 256;     // 3125
    int nb1 = (2540 + 255) / 256;       // 10
    int gnodeAgg = (NNODES + 3) / 4;

    // chunk-ordered CSR: counting sort by (dst, src>>12)
    zero_i32<<<nbB, 256, 0, stream>>>(cnt2, NB2);
    hist2_kernel<<<nbE, 256, 0, stream>>>(src, dst, cnt2, NEDGES);
    scan1_kernel<<<nbB, 256, 0, stream>>>(cnt2, cp, bs1, NB2);
    scan1_kernel<<<nb1, 256, 0, stream>>>(bs1, bs1s, bs2, 2540);
    scan2_kernel<<<1, 256, 0, stream>>>(bs2, nb1);
    scan3_kernel<<<nb1, 256, 0, stream>>>(bs1s, bs2, cursor2, 2540);
    scan3_kernel<<<nbB, 256, 0, stream>>>(cp, bs1s, cursor2, NB2);
    rowptr_kernel<<<(NNODES + 256) / 256, 256, 0, stream>>>(cp, row_ptr);
    fill2_kernel<<<nbE, 256, 0, stream>>>(src, dst, cp, cursor2, csr, NEDGES);

    dim3 gA((NNODES + 127) / 128, 2);  // M=128
    dim3 gB((NNODES + 127) / 128, 4);  // M=256

    gemm_mfma<32, true, 1><<<gA, 256, 0, stream>>>(x, W1, as1, ad1, hbuf, asrc, adst, NNODES, 128);
    aggregate_kernel<2, false, 1><<<gnodeAgg, 256, 0, stream>>>(hbuf, asrc, adst, csr, row_ptr, b1, buf1h, NNODES);

    gemm_mfma<32, false, 2><<<gA, 256, 0, stream>>>(buf1h, W2, as2, ad2, hbuf, asrc, adst, NNODES, 128);
    aggregate_kernel<2, false, 2><<<gnodeAgg, 256, 0, stream>>>(hbuf, asrc, adst, csr, row_ptr, b2, buf1h, NNODES);

    gemm_mfma<64, false, 3><<<gB, 256, 0, stream>>>(buf1h, W3, as3, ad3, hbuf, asrc, adst, NNODES, 256);
    aggregate_kernel<4, true, 3><<<gnodeAgg, 256, 0, stream>>>(hbuf, asrc, adst, csr, row_ptr, b3, outp, NNODES);
}